// Round 15
// baseline (396.723 us; speedup 1.0000x reference)
//
#include <hip/hip_runtime.h>
#include <stdint.h>

typedef float f32x4 __attribute__((ext_vector_type(4)));
typedef short s16x8 __attribute__((ext_vector_type(8)));
typedef unsigned short u16x4 __attribute__((ext_vector_type(4)));
typedef unsigned short u16x8 __attribute__((ext_vector_type(8)));

__device__ __forceinline__ unsigned short f2bf(float f) {
  union { float f; unsigned u; } v; v.f = f;
  unsigned r = v.u + 0x7fffu + ((v.u >> 16) & 1u);
  return (unsigned short)(r >> 16);
}

__device__ __forceinline__ float bf2f(unsigned short u) {
  union { unsigned u; float f; } v; v.u = ((unsigned)u) << 16;
  return v.f;
}

__device__ __forceinline__ void gld_lds16(const void* g, void* l) {
  __builtin_amdgcn_global_load_lds(
      (__attribute__((address_space(1))) void*)(void*)g,
      (__attribute__((address_space(3))) void*)l,
      16, 0, 0);
}

__device__ __forceinline__ double shfl_xor_dbl(double v, int m) {
  long long l = __double_as_longlong(v);
  int lo = (int)(l & 0xffffffffLL), hi = (int)(l >> 32);
  lo = __shfl_xor(lo, m, 64);
  hi = __shfl_xor(hi, m, 64);
  return __longlong_as_double(((long long)hi << 32) | (unsigned)lo);
}

// padded (128-row) prefix of counts, computed inline by each GEMM block
__device__ __forceinline__ int padded_base(const int* counts, int e) {
  int s = 0;
#pragma unroll
  for (int i = 0; i < 8; ++i) {
    int c = (counts[i] + 127) & ~127;
    s += (i < e) ? c : 0;
  }
  return s;
}

// -------- merged prep: router (blocks 0..NR-1) + weight transposes -------
// nRouter=1024 -> each wave routes exactly ONE token (shortest latency
// chain); router blocks get low bids so they start first and their
// latency hides under the transpose blocks' streaming.
__global__ __launch_bounds__(256) void k_prep(
    const float* __restrict__ x, const float* __restrict__ rw,
    const float* __restrict__ rb, unsigned short* __restrict__ xb,
    int* __restrict__ counts, uint2* __restrict__ lists,
    const float* __restrict__ w1, const float* __restrict__ w2,
    unsigned short* __restrict__ w1bT, unsigned short* __restrict__ w2bT,
    int T, int D, int H, int nRouter) {
  __shared__ float tile[64][65];
  int bid = blockIdx.x;
  int tid = threadIdx.x;

  if (bid < nRouter) {
    // ---------------- router path ----------------
    int lane = tid & 63;
    int wid = (bid * 256 + tid) >> 6;
    int nw = nRouter * 4;  // 256 threads = 4 waves per block
    for (int t = wid; t < T; t += nw) {
      double acc[8] = {0, 0, 0, 0, 0, 0, 0, 0};
      for (int j = lane * 4; j < D; j += 256) {
        float4 xv = *(const float4*)(x + (size_t)t * D + j);
        u16x4 o;
        o[0] = f2bf(xv.x); o[1] = f2bf(xv.y); o[2] = f2bf(xv.z); o[3] = f2bf(xv.w);
        *(u16x4*)(xb + (size_t)t * D + j) = o;
        float xs[4] = {xv.x, xv.y, xv.z, xv.w};
#pragma unroll
        for (int q = 0; q < 4; ++q) {
          const float* rp = rw + (size_t)(j + q) * 8;
#pragma unroll
          for (int e = 0; e < 8; ++e) acc[e] += (double)xs[q] * (double)rp[e];
        }
      }
#pragma unroll
      for (int e = 0; e < 8; ++e) {
#pragma unroll
        for (int off = 32; off >= 1; off >>= 1) acc[e] += shfl_xor_dbl(acc[e], off);
      }
      if (lane == 0) {
        double v0 = -1e300, v1 = -1e300; int e0 = 0, e1 = 0;
#pragma unroll
        for (int e = 0; e < 8; ++e) {
          double v = acc[e] + (double)rb[e];
          if (v > v0) { v1 = v0; e1 = e0; v0 = v; e0 = e; }
          else if (v > v1) { v1 = v; e1 = e; }
        }
        double ex = exp(v1 - v0);
        float g0 = (float)(1.0 / (1.0 + ex));
        float g1 = (float)(ex / (1.0 + ex));
        int s0 = atomicAdd(&counts[e0], 1);
        int s1 = atomicAdd(&counts[e1], 1);
        lists[(size_t)e0 * T + s0] = make_uint2((unsigned)t, __float_as_uint(g0));
        lists[(size_t)e1 * T + s1] = make_uint2((unsigned)t | 0x80000000u, __float_as_uint(g1));
      }
    }
    return;
  }

  // ---------------- transpose path ----------------
  int tilesPerMat = (D >> 6) * (H >> 6);      // same for w1 and w2
  int tb = bid - nRouter;
  int z = tb / tilesPerMat;                   // 0..15: z<8 -> w2[e], z>=8 -> w1[e]
  int txy = tb - z * tilesPerMat;
  int e = z & 7;
  bool is_w1 = z >= 8;
  int R = is_w1 ? D : H, C = is_w1 ? H : D;
  const size_t RC = (size_t)R * C;
  const float* s = (is_w1 ? w1 : w2) + (size_t)e * RC;
  unsigned short* d = (is_w1 ? w1bT : w2bT) + (size_t)e * RC;
  int tpc = C >> 6;
  int bx = txy % tpc, by = txy / tpc;
  int r0 = by * 64, c0 = bx * 64;
#pragma unroll
  for (int i = 0; i < 4; ++i) {
    int slot = tid + i * 256;
    int r = slot >> 4, c4 = (slot & 15) << 2;
    float4 v = *(const float4*)(s + (size_t)(r0 + r) * C + c0 + c4);
    tile[r][c4 + 0] = v.x; tile[r][c4 + 1] = v.y;
    tile[r][c4 + 2] = v.z; tile[r][c4 + 3] = v.w;
  }
  __syncthreads();
#pragma unroll
  for (int i = 0; i < 2; ++i) {
    int slot = tid + i * 256;
    int c = slot >> 3, r8 = (slot & 7) << 3;
    u16x8 o;
#pragma unroll
    for (int j = 0; j < 8; ++j) o[j] = f2bf(tile[r8 + j][c]);
    *(u16x8*)(d + (size_t)(c0 + c) * R + r0 + r8) = o;
  }
}

// ---------------- GEMM1: 128x128xBK64, single buffer, 4 blocks/CU --------
__global__ __launch_bounds__(256, 4) void k_gemm1(
    const unsigned short* __restrict__ xb, const unsigned short* __restrict__ w1bT,
    const float* __restrict__ b1, const int* __restrict__ counts,
    const uint2* __restrict__ lists,
    unsigned short* __restrict__ he, int T, int D, int H) {
  int e = blockIdx.z;
  int cnt = counts[e];
  int nwg = gridDim.x * gridDim.y;               // divisible by 8
  int flat = blockIdx.y * gridDim.x + blockIdx.x;
  int idx = (flat & 7) * (nwg >> 3) + (flat >> 3);
  int bn = idx / gridDim.y, bm = idx - bn * gridDim.y;
  int m0 = bm * 128;
  if (m0 >= cnt) return;
  int n0 = bn * 128;
  int baseE = padded_base(counts, e);
  int tid = threadIdx.x;

  __shared__ __align__(16) unsigned short As[128 * 64];
  __shared__ __align__(16) unsigned short Bs[128 * 64];

  const uint2* le = lists + (size_t)e * T;
  const unsigned short* srcA[4];
  const unsigned short* srcB[4];
#pragma unroll
  for (int i = 0; i < 4; ++i) {
    int row = (tid >> 3) + i * 32;
    int mrow = m0 + row; if (mrow > cnt - 1) mrow = cnt - 1;
    unsigned tok = le[mrow].x & 0x7fffffffu;
    int G = (tid & 7) ^ (row & 7);
    srcA[i] = xb + (size_t)tok * D + G * 8;
    srcB[i] = w1bT + ((size_t)e * H + n0 + row) * D + G * 8;
  }

  int lane = tid & 63;
  int wr = tid >> 7, wc = (tid >> 6) & 1;
  int lrow = lane & 15, lgrp = (lane >> 4) & 3;
  int mb = wr * 64, nb = wc * 64;
  int rsw = lrow & 7;

  f32x4 acc[4][4];
#pragma unroll
  for (int a = 0; a < 4; ++a)
#pragma unroll
    for (int b = 0; b < 4; ++b) acc[a][b] = (f32x4){0.f, 0.f, 0.f, 0.f};

  int nk = D >> 6;
  for (int kt = 0; kt < nk; ++kt) {
#pragma unroll
    for (int i = 0; i < 4; ++i) {
      gld_lds16(srcA[i], As + tid * 8 + i * 2048);
      gld_lds16(srcB[i], Bs + tid * 8 + i * 2048);
      srcA[i] += 64;
      srcB[i] += 64;
    }
    asm volatile("s_waitcnt vmcnt(0)" ::: "memory");
    __syncthreads();
#pragma unroll
    for (int ks = 0; ks < 2; ++ks) {
      s16x8 av[4], bv[4];
#pragma unroll
      for (int mf = 0; mf < 4; ++mf) {
        int row = mb + mf * 16 + lrow;
        int Gp = (ks * 4 + lgrp) ^ rsw;
        av[mf] = *(const s16x8*)(As + row * 64 + Gp * 8);
      }
#pragma unroll
      for (int nf = 0; nf < 4; ++nf) {
        int row = nb + nf * 16 + lrow;
        int Gp = (ks * 4 + lgrp) ^ rsw;
        bv[nf] = *(const s16x8*)(Bs + row * 64 + Gp * 8);
      }
#pragma unroll
      for (int mf = 0; mf < 4; ++mf)
#pragma unroll
        for (int nf = 0; nf < 4; ++nf)
          acc[mf][nf] = __builtin_amdgcn_mfma_f32_16x16x32_bf16(av[mf], bv[nf], acc[mf][nf], 0, 0, 0);
    }
    __syncthreads();
  }

#pragma unroll
  for (int nf = 0; nf < 4; ++nf) {
    int n = nb + nf * 16 + lrow;
    float b1v = b1[(size_t)e * H + n0 + n];
#pragma unroll
    for (int mf = 0; mf < 4; ++mf) {
      f32x4 v = acc[mf][nf];
#pragma unroll
      for (int j = 0; j < 4; ++j) {
        int gm = m0 + mb + mf * 16 + lgrp * 4 + j;
        float val = v[j] + b1v;
        val = val > 0.f ? val : 0.f;
        he[((size_t)baseE + gm) * H + n0 + n] = f2bf(val);
      }
    }
  }
}

// ------ GEMM2: 128x128xBK64, single buffer, K-split 2, 4 blocks/CU -------
__global__ __launch_bounds__(256, 4) void k_gemm2(
    const unsigned short* __restrict__ he, const unsigned short* __restrict__ w2bT,
    const float* __restrict__ b2, const int* __restrict__ counts,
    const uint2* __restrict__ lists,
    unsigned short* __restrict__ y, int T, int H, int D) {
  int z = blockIdx.z;
  int e = z >> 1, ksp = z & 1;
  int cnt = counts[e];
  int nwg = gridDim.x * gridDim.y;
  int flat = blockIdx.y * gridDim.x + blockIdx.x;
  int idx = (flat & 7) * (nwg >> 3) + (flat >> 3);
  int bn = idx / gridDim.y, bm = idx - bn * gridDim.y;
  int m0 = bm * 128;
  if (m0 >= cnt) return;
  int n0 = bn * 128;
  int baseE = padded_base(counts, e);
  int tid = threadIdx.x;
  int koff = ksp * (H >> 1);

  __shared__ __align__(16) unsigned short As[128 * 64];
  __shared__ __align__(16) unsigned short Bs[128 * 64];

  const uint2* le = lists + (size_t)e * T;
  const unsigned short* srcA[4];
  const unsigned short* srcB[4];
#pragma unroll
  for (int i = 0; i < 4; ++i) {
    int row = (tid >> 3) + i * 32;
    int G = (tid & 7) ^ (row & 7);
    srcA[i] = he + ((size_t)baseE + m0 + row) * H + koff + G * 8;
    srcB[i] = w2bT + ((size_t)e * D + n0 + row) * H + koff + G * 8;
  }

  int lane = tid & 63;
  int wr = tid >> 7, wc = (tid >> 6) & 1;
  int lrow = lane & 15, lgrp = (lane >> 4) & 3;
  int mb = wr * 64, nb = wc * 64;
  int rsw = lrow & 7;

  f32x4 acc[4][4];
#pragma unroll
  for (int a = 0; a < 4; ++a)
#pragma unroll
    for (int b = 0; b < 4; ++b) acc[a][b] = (f32x4){0.f, 0.f, 0.f, 0.f};

  int nk = H >> 7;  // (H/2)/64 = 32 iters per split half
  for (int kt = 0; kt < nk; ++kt) {
#pragma unroll
    for (int i = 0; i < 4; ++i) {
      gld_lds16(srcA[i], As + tid * 8 + i * 2048);
      gld_lds16(srcB[i], Bs + tid * 8 + i * 2048);
      srcA[i] += 64;
      srcB[i] += 64;
    }
    asm volatile("s_waitcnt vmcnt(0)" ::: "memory");
    __syncthreads();
#pragma unroll
    for (int ks = 0; ks < 2; ++ks) {
      s16x8 av[4], bv[4];
#pragma unroll
      for (int mf = 0; mf < 4; ++mf) {
        int row = mb + mf * 16 + lrow;
        int Gp = (ks * 4 + lgrp) ^ rsw;
        av[mf] = *(const s16x8*)(As + row * 64 + Gp * 8);
      }
#pragma unroll
      for (int nf = 0; nf < 4; ++nf) {
        int row = nb + nf * 16 + lrow;
        int Gp = (ks * 4 + lgrp) ^ rsw;
        bv[nf] = *(const s16x8*)(Bs + row * 64 + Gp * 8);
      }
#pragma unroll
      for (int mf = 0; mf < 4; ++mf)
#pragma unroll
        for (int nf = 0; nf < 4; ++nf)
          acc[mf][nf] = __builtin_amdgcn_mfma_f32_16x16x32_bf16(av[mf], bv[nf], acc[mf][nf], 0, 0, 0);
    }
    __syncthreads();
  }

  float b2v[4];
#pragma unroll
  for (int nf = 0; nf < 4; ++nf)
    b2v[nf] = (ksp == 0) ? b2[(size_t)e * D + n0 + nb + nf * 16 + lrow] : 0.f;

#pragma unroll
  for (int mf = 0; mf < 4; ++mf) {
#pragma unroll
    for (int j = 0; j < 4; ++j) {
      int gm = m0 + mb + mf * 16 + lgrp * 4 + j;
      if (gm < cnt) {
        uint2 en = le[gm];
        unsigned tok = en.x & 0x7fffffffu;
        unsigned rank = en.x >> 31;
        float g = __uint_as_float(en.y);
        unsigned short* yrow = y + (((size_t)(rank * 2 + ksp)) * T + tok) * D + n0;
#pragma unroll
        for (int nf = 0; nf < 4; ++nf)
          yrow[nb + nf * 16 + lrow] = f2bf((acc[mf][nf][j] + b2v[nf]) * g);
      }
    }
  }
}

// ---------------- combine: out = sum of 4 bf16 y-slices -------------------
__global__ __launch_bounds__(256) void k_combine(
    const unsigned short* __restrict__ y, float* __restrict__ out, size_t n8) {
  size_t i = (size_t)blockIdx.x * 256 + threadIdx.x;
  size_t stride = (size_t)gridDim.x * 256;
  size_t n = n8 * 8;
  for (; i < n8; i += stride) {
    s16x8 a = *(const s16x8*)(y + i * 8);
    s16x8 b = *(const s16x8*)(y + n + i * 8);
    s16x8 c = *(const s16x8*)(y + 2 * n + i * 8);
    s16x8 d = *(const s16x8*)(y + 3 * n + i * 8);
    float r[8];
#pragma unroll
    for (int j = 0; j < 8; ++j)
      r[j] = bf2f((unsigned short)a[j]) + bf2f((unsigned short)b[j]) +
             bf2f((unsigned short)c[j]) + bf2f((unsigned short)d[j]);
    float4* o = (float4*)(out + i * 8);
    o[0] = make_float4(r[0], r[1], r[2], r[3]);
    o[1] = make_float4(r[4], r[5], r[6], r[7]);
  }
}

extern "C" void kernel_launch(void* const* d_in, const int* in_sizes, int n_in,
                              void* d_out, int out_size, void* d_ws, size_t ws_size,
                              hipStream_t stream) {
  const float* x  = (const float*)d_in[0];
  const float* rw = (const float*)d_in[1];
  const float* rb = (const float*)d_in[2];
  const float* w1 = (const float*)d_in[3];
  const float* b1 = (const float*)d_in[4];
  const float* w2 = (const float*)d_in[5];
  const float* b2 = (const float*)d_in[6];
  float* out = (float*)d_out;

  int E = in_sizes[2];
  int D = in_sizes[1] / E;
  int H = in_sizes[4] / E;
  int T = in_sizes[0] / D;

  char* ws = (char*)d_ws;
  size_t off = 0;
  auto alloc = [&](size_t bytes) -> void* {
    void* p = ws + off;
    off = (off + bytes + 255) & ~(size_t)255;
    return p;
  };
  unsigned short* xb   = (unsigned short*)alloc((size_t)T * D * 2);
  unsigned short* w1bT = (unsigned short*)alloc((size_t)E * D * H * 2);
  unsigned short* w2bT = (unsigned short*)alloc((size_t)E * D * H * 2);
  unsigned short* he   = (unsigned short*)alloc(((size_t)2 * T + E * 128) * H * 2);
  unsigned short* y    = (unsigned short*)alloc((size_t)4 * T * D * 2);  // bf16 partials
  int* counts          = (int*)alloc(64);
  uint2* lists         = (uint2*)alloc((size_t)E * T * 8);

  hipMemsetAsync(counts, 0, 64, stream);

  dim3 b256(256);
  // merged prep: 1024 router blocks (1 token/wave) first, transposes after
  int nRouter = 1024;
  int nTrans = (D / 64) * (H / 64) * 2 * E;
  k_prep<<<dim3(nRouter + nTrans), b256, 0, stream>>>(
      x, rw, rb, xb, counts, lists, w1, w2, w1bT, w2bT, T, D, H, nRouter);

  int mt = (T + 127) / 128;  // 32
  k_gemm1<<<dim3(H / 128, mt, E), b256, 0, stream>>>(xb, w1bT, b1, counts, lists, he, T, D, H);
  k_gemm2<<<dim3(D / 128, mt, E * 2), b256, 0, stream>>>(he, w2bT, b2, counts, lists, y, T, H, D);

  size_t n8 = (size_t)T * D / 8;
  k_combine<<<dim3(2048), b256, 0, stream>>>(y, out, n8);
}

// Round 16
// 345.816 us; speedup vs baseline: 1.1472x; 1.1472x over previous
//
#include <hip/hip_runtime.h>
#include <stdint.h>

typedef float f32x4 __attribute__((ext_vector_type(4)));
typedef short s16x8 __attribute__((ext_vector_type(8)));
typedef unsigned short u16x4 __attribute__((ext_vector_type(4)));
typedef unsigned short u16x8 __attribute__((ext_vector_type(8)));

__device__ __forceinline__ unsigned short f2bf(float f) {
  union { float f; unsigned u; } v; v.f = f;
  unsigned r = v.u + 0x7fffu + ((v.u >> 16) & 1u);
  return (unsigned short)(r >> 16);
}

__device__ __forceinline__ float bf2f(unsigned short u) {
  union { unsigned u; float f; } v; v.u = ((unsigned)u) << 16;
  return v.f;
}

__device__ __forceinline__ void gld_lds16(const void* g, void* l) {
  __builtin_amdgcn_global_load_lds(
      (__attribute__((address_space(1))) void*)(void*)g,
      (__attribute__((address_space(3))) void*)l,
      16, 0, 0);
}

__device__ __forceinline__ double shfl_xor_dbl(double v, int m) {
  long long l = __double_as_longlong(v);
  int lo = (int)(l & 0xffffffffLL), hi = (int)(l >> 32);
  lo = __shfl_xor(lo, m, 64);
  hi = __shfl_xor(hi, m, 64);
  return __longlong_as_double(((long long)hi << 32) | (unsigned)lo);
}

// padded (128-row) prefix of counts, computed inline by each GEMM block
__device__ __forceinline__ int padded_base(const int* counts, int e) {
  int s = 0;
#pragma unroll
  for (int i = 0; i < 8; ++i) {
    int c = (counts[i] + 127) & ~127;
    s += (i < e) ? c : 0;
  }
  return s;
}

// -------- merged prep: router (blocks 0..NR-1) + weight transposes -------
// nRouter=256 (R14 optimum): ~1 router block per CU interleaves into the
// 16K-block transpose stream; router VALU hides under transpose HBM stalls.
// (R15 A/B: nRouter=1024 displaced the BW stream from the initial CU fill
// and regressed 346->397 us. Keep 256.)
__global__ __launch_bounds__(256) void k_prep(
    const float* __restrict__ x, const float* __restrict__ rw,
    const float* __restrict__ rb, unsigned short* __restrict__ xb,
    int* __restrict__ counts, uint2* __restrict__ lists,
    const float* __restrict__ w1, const float* __restrict__ w2,
    unsigned short* __restrict__ w1bT, unsigned short* __restrict__ w2bT,
    int T, int D, int H, int nRouter) {
  __shared__ float tile[64][65];
  int bid = blockIdx.x;
  int tid = threadIdx.x;

  if (bid < nRouter) {
    // ---------------- router path ----------------
    int lane = tid & 63;
    int wid = (bid * 256 + tid) >> 6;
    int nw = nRouter * 4;  // 256 threads = 4 waves per block
    for (int t = wid; t < T; t += nw) {
      double acc[8] = {0, 0, 0, 0, 0, 0, 0, 0};
      for (int j = lane * 4; j < D; j += 256) {
        float4 xv = *(const float4*)(x + (size_t)t * D + j);
        u16x4 o;
        o[0] = f2bf(xv.x); o[1] = f2bf(xv.y); o[2] = f2bf(xv.z); o[3] = f2bf(xv.w);
        *(u16x4*)(xb + (size_t)t * D + j) = o;
        float xs[4] = {xv.x, xv.y, xv.z, xv.w};
#pragma unroll
        for (int q = 0; q < 4; ++q) {
          const float* rp = rw + (size_t)(j + q) * 8;
#pragma unroll
          for (int e = 0; e < 8; ++e) acc[e] += (double)xs[q] * (double)rp[e];
        }
      }
#pragma unroll
      for (int e = 0; e < 8; ++e) {
#pragma unroll
        for (int off = 32; off >= 1; off >>= 1) acc[e] += shfl_xor_dbl(acc[e], off);
      }
      if (lane == 0) {
        double v0 = -1e300, v1 = -1e300; int e0 = 0, e1 = 0;
#pragma unroll
        for (int e = 0; e < 8; ++e) {
          double v = acc[e] + (double)rb[e];
          if (v > v0) { v1 = v0; e1 = e0; v0 = v; e0 = e; }
          else if (v > v1) { v1 = v; e1 = e; }
        }
        double ex = exp(v1 - v0);
        float g0 = (float)(1.0 / (1.0 + ex));
        float g1 = (float)(ex / (1.0 + ex));
        int s0 = atomicAdd(&counts[e0], 1);
        int s1 = atomicAdd(&counts[e1], 1);
        lists[(size_t)e0 * T + s0] = make_uint2((unsigned)t, __float_as_uint(g0));
        lists[(size_t)e1 * T + s1] = make_uint2((unsigned)t | 0x80000000u, __float_as_uint(g1));
      }
    }
    return;
  }

  // ---------------- transpose path ----------------
  int tilesPerMat = (D >> 6) * (H >> 6);      // same for w1 and w2
  int tb = bid - nRouter;
  int z = tb / tilesPerMat;                   // 0..15: z<8 -> w2[e], z>=8 -> w1[e]
  int txy = tb - z * tilesPerMat;
  int e = z & 7;
  bool is_w1 = z >= 8;
  int R = is_w1 ? D : H, C = is_w1 ? H : D;
  const size_t RC = (size_t)R * C;
  const float* s = (is_w1 ? w1 : w2) + (size_t)e * RC;
  unsigned short* d = (is_w1 ? w1bT : w2bT) + (size_t)e * RC;
  int tpc = C >> 6;
  int bx = txy % tpc, by = txy / tpc;
  int r0 = by * 64, c0 = bx * 64;
#pragma unroll
  for (int i = 0; i < 4; ++i) {
    int slot = tid + i * 256;
    int r = slot >> 4, c4 = (slot & 15) << 2;
    float4 v = *(const float4*)(s + (size_t)(r0 + r) * C + c0 + c4);
    tile[r][c4 + 0] = v.x; tile[r][c4 + 1] = v.y;
    tile[r][c4 + 2] = v.z; tile[r][c4 + 3] = v.w;
  }
  __syncthreads();
#pragma unroll
  for (int i = 0; i < 2; ++i) {
    int slot = tid + i * 256;
    int c = slot >> 3, r8 = (slot & 7) << 3;
    u16x8 o;
#pragma unroll
    for (int j = 0; j < 8; ++j) o[j] = f2bf(tile[r8 + j][c]);
    *(u16x8*)(d + (size_t)(c0 + c) * R + r0 + r8) = o;
  }
}

// ---------------- GEMM1: 128x128xBK64, single buffer, 4 blocks/CU --------
__global__ __launch_bounds__(256, 4) void k_gemm1(
    const unsigned short* __restrict__ xb, const unsigned short* __restrict__ w1bT,
    const float* __restrict__ b1, const int* __restrict__ counts,
    const uint2* __restrict__ lists,
    unsigned short* __restrict__ he, int T, int D, int H) {
  int e = blockIdx.z;
  int cnt = counts[e];
  int nwg = gridDim.x * gridDim.y;               // divisible by 8
  int flat = blockIdx.y * gridDim.x + blockIdx.x;
  int idx = (flat & 7) * (nwg >> 3) + (flat >> 3);
  int bn = idx / gridDim.y, bm = idx - bn * gridDim.y;
  int m0 = bm * 128;
  if (m0 >= cnt) return;
  int n0 = bn * 128;
  int baseE = padded_base(counts, e);
  int tid = threadIdx.x;

  __shared__ __align__(16) unsigned short As[128 * 64];
  __shared__ __align__(16) unsigned short Bs[128 * 64];

  const uint2* le = lists + (size_t)e * T;
  const unsigned short* srcA[4];
  const unsigned short* srcB[4];
#pragma unroll
  for (int i = 0; i < 4; ++i) {
    int row = (tid >> 3) + i * 32;
    int mrow = m0 + row; if (mrow > cnt - 1) mrow = cnt - 1;
    unsigned tok = le[mrow].x & 0x7fffffffu;
    int G = (tid & 7) ^ (row & 7);
    srcA[i] = xb + (size_t)tok * D + G * 8;
    srcB[i] = w1bT + ((size_t)e * H + n0 + row) * D + G * 8;
  }

  int lane = tid & 63;
  int wr = tid >> 7, wc = (tid >> 6) & 1;
  int lrow = lane & 15, lgrp = (lane >> 4) & 3;
  int mb = wr * 64, nb = wc * 64;
  int rsw = lrow & 7;

  f32x4 acc[4][4];
#pragma unroll
  for (int a = 0; a < 4; ++a)
#pragma unroll
    for (int b = 0; b < 4; ++b) acc[a][b] = (f32x4){0.f, 0.f, 0.f, 0.f};

  int nk = D >> 6;
  for (int kt = 0; kt < nk; ++kt) {
#pragma unroll
    for (int i = 0; i < 4; ++i) {
      gld_lds16(srcA[i], As + tid * 8 + i * 2048);
      gld_lds16(srcB[i], Bs + tid * 8 + i * 2048);
      srcA[i] += 64;
      srcB[i] += 64;
    }
    asm volatile("s_waitcnt vmcnt(0)" ::: "memory");
    __syncthreads();
#pragma unroll
    for (int ks = 0; ks < 2; ++ks) {
      s16x8 av[4], bv[4];
#pragma unroll
      for (int mf = 0; mf < 4; ++mf) {
        int row = mb + mf * 16 + lrow;
        int Gp = (ks * 4 + lgrp) ^ rsw;
        av[mf] = *(const s16x8*)(As + row * 64 + Gp * 8);
      }
#pragma unroll
      for (int nf = 0; nf < 4; ++nf) {
        int row = nb + nf * 16 + lrow;
        int Gp = (ks * 4 + lgrp) ^ rsw;
        bv[nf] = *(const s16x8*)(Bs + row * 64 + Gp * 8);
      }
#pragma unroll
      for (int mf = 0; mf < 4; ++mf)
#pragma unroll
        for (int nf = 0; nf < 4; ++nf)
          acc[mf][nf] = __builtin_amdgcn_mfma_f32_16x16x32_bf16(av[mf], bv[nf], acc[mf][nf], 0, 0, 0);
    }
    __syncthreads();
  }

#pragma unroll
  for (int nf = 0; nf < 4; ++nf) {
    int n = nb + nf * 16 + lrow;
    float b1v = b1[(size_t)e * H + n0 + n];
#pragma unroll
    for (int mf = 0; mf < 4; ++mf) {
      f32x4 v = acc[mf][nf];
#pragma unroll
      for (int j = 0; j < 4; ++j) {
        int gm = m0 + mb + mf * 16 + lgrp * 4 + j;
        float val = v[j] + b1v;
        val = val > 0.f ? val : 0.f;
        he[((size_t)baseE + gm) * H + n0 + n] = f2bf(val);
      }
    }
  }
}

// ------ GEMM2: 128x128xBK64, single buffer, K-split 2, 4 blocks/CU -------
__global__ __launch_bounds__(256, 4) void k_gemm2(
    const unsigned short* __restrict__ he, const unsigned short* __restrict__ w2bT,
    const float* __restrict__ b2, const int* __restrict__ counts,
    const uint2* __restrict__ lists,
    unsigned short* __restrict__ y, int T, int H, int D) {
  int z = blockIdx.z;
  int e = z >> 1, ksp = z & 1;
  int cnt = counts[e];
  int nwg = gridDim.x * gridDim.y;
  int flat = blockIdx.y * gridDim.x + blockIdx.x;
  int idx = (flat & 7) * (nwg >> 3) + (flat >> 3);
  int bn = idx / gridDim.y, bm = idx - bn * gridDim.y;
  int m0 = bm * 128;
  if (m0 >= cnt) return;
  int n0 = bn * 128;
  int baseE = padded_base(counts, e);
  int tid = threadIdx.x;
  int koff = ksp * (H >> 1);

  __shared__ __align__(16) unsigned short As[128 * 64];
  __shared__ __align__(16) unsigned short Bs[128 * 64];

  const uint2* le = lists + (size_t)e * T;
  const unsigned short* srcA[4];
  const unsigned short* srcB[4];
#pragma unroll
  for (int i = 0; i < 4; ++i) {
    int row = (tid >> 3) + i * 32;
    int G = (tid & 7) ^ (row & 7);
    srcA[i] = he + ((size_t)baseE + m0 + row) * H + koff + G * 8;
    srcB[i] = w2bT + ((size_t)e * D + n0 + row) * H + koff + G * 8;
  }

  int lane = tid & 63;
  int wr = tid >> 7, wc = (tid >> 6) & 1;
  int lrow = lane & 15, lgrp = (lane >> 4) & 3;
  int mb = wr * 64, nb = wc * 64;
  int rsw = lrow & 7;

  f32x4 acc[4][4];
#pragma unroll
  for (int a = 0; a < 4; ++a)
#pragma unroll
    for (int b = 0; b < 4; ++b) acc[a][b] = (f32x4){0.f, 0.f, 0.f, 0.f};

  int nk = H >> 7;  // (H/2)/64 = 32 iters per split half
  for (int kt = 0; kt < nk; ++kt) {
#pragma unroll
    for (int i = 0; i < 4; ++i) {
      gld_lds16(srcA[i], As + tid * 8 + i * 2048);
      gld_lds16(srcB[i], Bs + tid * 8 + i * 2048);
      srcA[i] += 64;
      srcB[i] += 64;
    }
    asm volatile("s_waitcnt vmcnt(0)" ::: "memory");
    __syncthreads();
#pragma unroll
    for (int ks = 0; ks < 2; ++ks) {
      s16x8 av[4], bv[4];
#pragma unroll
      for (int mf = 0; mf < 4; ++mf) {
        int row = mb + mf * 16 + lrow;
        int Gp = (ks * 4 + lgrp) ^ rsw;
        av[mf] = *(const s16x8*)(As + row * 64 + Gp * 8);
      }
#pragma unroll
      for (int nf = 0; nf < 4; ++nf) {
        int row = nb + nf * 16 + lrow;
        int Gp = (ks * 4 + lgrp) ^ rsw;
        bv[nf] = *(const s16x8*)(Bs + row * 64 + Gp * 8);
      }
#pragma unroll
      for (int mf = 0; mf < 4; ++mf)
#pragma unroll
        for (int nf = 0; nf < 4; ++nf)
          acc[mf][nf] = __builtin_amdgcn_mfma_f32_16x16x32_bf16(av[mf], bv[nf], acc[mf][nf], 0, 0, 0);
    }
    __syncthreads();
  }

  float b2v[4];
#pragma unroll
  for (int nf = 0; nf < 4; ++nf)
    b2v[nf] = (ksp == 0) ? b2[(size_t)e * D + n0 + nb + nf * 16 + lrow] : 0.f;

#pragma unroll
  for (int mf = 0; mf < 4; ++mf) {
#pragma unroll
    for (int j = 0; j < 4; ++j) {
      int gm = m0 + mb + mf * 16 + lgrp * 4 + j;
      if (gm < cnt) {
        uint2 en = le[gm];
        unsigned tok = en.x & 0x7fffffffu;
        unsigned rank = en.x >> 31;
        float g = __uint_as_float(en.y);
        unsigned short* yrow = y + (((size_t)(rank * 2 + ksp)) * T + tok) * D + n0;
#pragma unroll
        for (int nf = 0; nf < 4; ++nf)
          yrow[nb + nf * 16 + lrow] = f2bf((acc[mf][nf][j] + b2v[nf]) * g);
      }
    }
  }
}

// ---------------- combine: out = sum of 4 bf16 y-slices -------------------
__global__ __launch_bounds__(256) void k_combine(
    const unsigned short* __restrict__ y, float* __restrict__ out, size_t n8) {
  size_t i = (size_t)blockIdx.x * 256 + threadIdx.x;
  size_t stride = (size_t)gridDim.x * 256;
  size_t n = n8 * 8;
  for (; i < n8; i += stride) {
    s16x8 a = *(const s16x8*)(y + i * 8);
    s16x8 b = *(const s16x8*)(y + n + i * 8);
    s16x8 c = *(const s16x8*)(y + 2 * n + i * 8);
    s16x8 d = *(const s16x8*)(y + 3 * n + i * 8);
    float r[8];
#pragma unroll
    for (int j = 0; j < 8; ++j)
      r[j] = bf2f((unsigned short)a[j]) + bf2f((unsigned short)b[j]) +
             bf2f((unsigned short)c[j]) + bf2f((unsigned short)d[j]);
    float4* o = (float4*)(out + i * 8);
    o[0] = make_float4(r[0], r[1], r[2], r[3]);
    o[1] = make_float4(r[4], r[5], r[6], r[7]);
  }
}

extern "C" void kernel_launch(void* const* d_in, const int* in_sizes, int n_in,
                              void* d_out, int out_size, void* d_ws, size_t ws_size,
                              hipStream_t stream) {
  const float* x  = (const float*)d_in[0];
  const float* rw = (const float*)d_in[1];
  const float* rb = (const float*)d_in[2];
  const float* w1 = (const float*)d_in[3];
  const float* b1 = (const float*)d_in[4];
  const float* w2 = (const float*)d_in[5];
  const float* b2 = (const float*)d_in[6];
  float* out = (float*)d_out;

  int E = in_sizes[2];
  int D = in_sizes[1] / E;
  int H = in_sizes[4] / E;
  int T = in_sizes[0] / D;

  char* ws = (char*)d_ws;
  size_t off = 0;
  auto alloc = [&](size_t bytes) -> void* {
    void* p = ws + off;
    off = (off + bytes + 255) & ~(size_t)255;
    return p;
  };
  unsigned short* xb   = (unsigned short*)alloc((size_t)T * D * 2);
  unsigned short* w1bT = (unsigned short*)alloc((size_t)E * D * H * 2);
  unsigned short* w2bT = (unsigned short*)alloc((size_t)E * D * H * 2);
  unsigned short* he   = (unsigned short*)alloc(((size_t)2 * T + E * 128) * H * 2);
  unsigned short* y    = (unsigned short*)alloc((size_t)4 * T * D * 2);  // bf16 partials
  int* counts          = (int*)alloc(64);
  uint2* lists         = (uint2*)alloc((size_t)E * T * 8);

  hipMemsetAsync(counts, 0, 64, stream);

  dim3 b256(256);
  // merged prep: 256 router blocks (R14 optimum) + 16384 transpose blocks
  int nRouter = 256;
  int nTrans = (D / 64) * (H / 64) * 2 * E;
  k_prep<<<dim3(nRouter + nTrans), b256, 0, stream>>>(
      x, rw, rb, xb, counts, lists, w1, w2, w1bT, w2bT, T, D, H, nRouter);

  int mt = (T + 127) / 128;  // 32
  k_gemm1<<<dim3(H / 128, mt, E), b256, 0, stream>>>(xb, w1bT, b1, counts, lists, he, T, D, H);
  k_gemm2<<<dim3(D / 128, mt, E * 2), b256, 0, stream>>>(he, w2bT, b2, counts, lists, y, T, H, D);

  size_t n8 = (size_t)T * D / 8;
  k_combine<<<dim3(2048), b256, 0, stream>>>(y, out, n8);
}